// Round 4
// baseline (95.394 us; speedup 1.0000x reference)
//
#include <hip/hip_runtime.h>

// Problem: B=4096, D=2, H=2048.
// e = sum_d enc[b,d,h]; d = sum_d dec[b,d,h]; S = e @ d^T (4096x4096)
// M = S on diag, -S off diag; LL = log_sigmoid(M)
// logLoss = -(sum(LL) + 39*sum(diag LL))/B ; diagonalLoss = -40*sum(diag LL)/B

#define BDIM 4096
#define HDIM 2048
#define BM 256
#define BN 256
#define HK 32                       // half-tile K depth
#define NH (HDIM / HK)              // 64 half-tiles
#define NBLK ((BDIM/BM) * (BDIM/BN))  // 256 blocks

typedef __attribute__((ext_vector_type(8))) short bf16x8;
typedef __attribute__((ext_vector_type(4))) float f32x4;

__device__ __forceinline__ unsigned short f2bf(float f) {
    unsigned int u = __float_as_uint(f);
    unsigned int r = (u + 0x7FFFu + ((u >> 16) & 1u)) >> 16;
    return (unsigned short)r;
}

__device__ __forceinline__ void gll16(const void* g, void* l) {
    __builtin_amdgcn_global_load_lds(
        (const __attribute__((address_space(1))) unsigned int*)g,
        (__attribute__((address_space(3))) unsigned int*)l,
        16, 0, 0);
}

// ---------------- Kernel 1: D-reduce + cast to bf16 ----------------
__global__ void reduce_cast(const float4* __restrict__ enc,
                            const float4* __restrict__ dec,
                            uint4* __restrict__ eb,
                            uint4* __restrict__ db) {
    int idx = blockIdx.x * blockDim.x + threadIdx.x;   // 0..1048575
    int b  = idx >> 8;
    int ch = idx & 255;
    int f4 = b * 1024 + ch * 2;

    {
        float4 a0 = enc[f4],       a1 = enc[f4 + 1];
        float4 c0 = enc[f4 + 512], c1 = enc[f4 + 512 + 1];
        uint4 o;
        o.x = (unsigned int)f2bf(a0.x + c0.x) | ((unsigned int)f2bf(a0.y + c0.y) << 16);
        o.y = (unsigned int)f2bf(a0.z + c0.z) | ((unsigned int)f2bf(a0.w + c0.w) << 16);
        o.z = (unsigned int)f2bf(a1.x + c1.x) | ((unsigned int)f2bf(a1.y + c1.y) << 16);
        o.w = (unsigned int)f2bf(a1.z + c1.z) | ((unsigned int)f2bf(a1.w + c1.w) << 16);
        eb[idx] = o;
    }
    {
        float4 a0 = dec[f4],       a1 = dec[f4 + 1];
        float4 c0 = dec[f4 + 512], c1 = dec[f4 + 512 + 1];
        uint4 o;
        o.x = (unsigned int)f2bf(a0.x + c0.x) | ((unsigned int)f2bf(a0.y + c0.y) << 16);
        o.y = (unsigned int)f2bf(a0.z + c0.z) | ((unsigned int)f2bf(a0.w + c0.w) << 16);
        o.z = (unsigned int)f2bf(a1.x + c1.x) | ((unsigned int)f2bf(a1.y + c1.y) << 16);
        o.w = (unsigned int)f2bf(a1.z + c1.z) | ((unsigned int)f2bf(a1.w + c1.w) << 16);
        db[idx] = o;
    }
}

// ---------------- Kernel 2: 8-phase pipelined 256x256 GEMM + fused log-sigmoid ----------------
// 8 waves (2M x 4N), per-wave 128x64 output, acc[8][4] f32x4.
// LDS: ring of 4 slots, each A[256][32] + B[256][32] bf16 = 32 KiB -> 128 KiB.
// Per half-tile h (K=32): 2 phases of 16 MFMA; per phase issue 2 global_load_lds
// for slot h+3 (depth-3 prefetch); counted vmcnt(8) once per half-tile.
// NOTE: no lgkmcnt(0)/sched_barrier before MFMA — C-level ds_read deps let the
// compiler emit fine-grained lgkmcnt interleaved with MFMAs (rule #18 applies
// to inline-asm reads only; pinning here was the m141 anti-pattern).
__global__ __launch_bounds__(512, 2) void gemm_reduce(
        const unsigned short* __restrict__ eb,
        const unsigned short* __restrict__ db,
        float* __restrict__ pall,
        float* __restrict__ pdiag) {
    __shared__ __align__(16) unsigned short lds[4 * 16384];  // 128 KiB

    const int tid  = threadIdx.x;
    const int lane = tid & 63;
    const int wid  = tid >> 6;          // 0..7
    const int wr   = wid >> 2;          // 0..1  (M)
    const int wc   = wid & 3;           // 0..3  (N)
    const int bm   = blockIdx.y, bn = blockIdx.x;
    const int row0 = bm * BM, col0 = bn * BN;

    const int fr = lane & 15;                        // fragment row
    const int sl = ((lane >> 4) + (fr >> 1)) & 3;    // swizzled 16B slot (read side)

    // staging: thread t writes LDS linear (row = t>>2, slot = t&3) within an 8KB chunk;
    // inverse-rotated global source col so read-side rotation sees linear k.
    const int su = tid >> 2;                         // row in 128-row chunk
    const int sg = ((tid & 3) - (su >> 1)) & 3;      // global 16B slot this thread fetches

    f32x4 acc[8][4] = {};

#define STAGE_A(s, kt) {                                                        \
    gll16(eb + (size_t)(row0 + su) * HDIM + (kt) + sg * 8,                      \
          &lds[(s) * 16384 + tid * 8]);                                         \
    gll16(eb + (size_t)(row0 + 128 + su) * HDIM + (kt) + sg * 8,                \
          &lds[(s) * 16384 + 4096 + tid * 8]); }
#define STAGE_B(s, kt) {                                                        \
    gll16(db + (size_t)(col0 + su) * HDIM + (kt) + sg * 8,                      \
          &lds[(s) * 16384 + 8192 + tid * 8]);                                  \
    gll16(db + (size_t)(col0 + 128 + su) * HDIM + (kt) + sg * 8,                \
          &lds[(s) * 16384 + 8192 + 4096 + tid * 8]); }

    // prologue: slots 0,1,2 (12 loads in flight)
    STAGE_A(0, 0)  STAGE_B(0, 0)
    STAGE_A(1, HK) STAGE_B(1, HK)
    STAGE_A(2, 2 * HK) STAGE_B(2, 2 * HK)
    asm volatile("s_waitcnt vmcnt(8)" ::: "memory");   // slot 0 landed
    __builtin_amdgcn_s_barrier();

#pragma unroll 4
    for (int h = 0; h < NH; ++h) {
        const unsigned short* S = &lds[(h & 3) * 16384];
        bf16x8 af[4], bf[4];

        // ---- phase 0: ds A m0-3 + B n0-3; stage A-half of slot h+3; MFMA upper ----
#pragma unroll
        for (int m = 0; m < 4; ++m)
            af[m] = *(const bf16x8*)&S[(wr * 128 + m * 16 + fr) * 32 + sl * 8];
#pragma unroll
        for (int n = 0; n < 4; ++n)
            bf[n] = *(const bf16x8*)&S[8192 + (wc * 64 + n * 16 + fr) * 32 + sl * 8];
        if (h + 3 < NH) STAGE_A((h + 3) & 3, (h + 3) * HK)
        __builtin_amdgcn_s_barrier();
        __builtin_amdgcn_s_setprio(1);
#pragma unroll
        for (int m = 0; m < 4; ++m)
#pragma unroll
            for (int n = 0; n < 4; ++n)
                acc[m][n] = __builtin_amdgcn_mfma_f32_16x16x32_bf16(
                    af[m], bf[n], acc[m][n], 0, 0, 0);
        __builtin_amdgcn_s_setprio(0);
        __builtin_amdgcn_s_barrier();

        // ---- phase 1: ds A m4-7; stage B-half of slot h+3; MFMA lower ----
#pragma unroll
        for (int m = 0; m < 4; ++m)
            af[m] = *(const bf16x8*)&S[(wr * 128 + (4 + m) * 16 + fr) * 32 + sl * 8];
        if (h + 3 < NH) STAGE_B((h + 3) & 3, (h + 3) * HK)
        __builtin_amdgcn_s_barrier();
        __builtin_amdgcn_s_setprio(1);
#pragma unroll
        for (int m = 0; m < 4; ++m)
#pragma unroll
            for (int n = 0; n < 4; ++n)
                acc[4 + m][n] = __builtin_amdgcn_mfma_f32_16x16x32_bf16(
                    af[m], bf[n], acc[4 + m][n], 0, 0, 0);
        __builtin_amdgcn_s_setprio(0);
        // counted drain: slot h+1 must be landed before next iteration reads it
        if (h < NH - 3)       { asm volatile("s_waitcnt vmcnt(8)" ::: "memory"); }
        else if (h == NH - 3) { asm volatile("s_waitcnt vmcnt(4)" ::: "memory"); }
        else if (h == NH - 2) { asm volatile("s_waitcnt vmcnt(0)" ::: "memory"); }
        __builtin_amdgcn_s_barrier();
    }
#undef STAGE_A
#undef STAGE_B

    // ---- epilogue: log-sigmoid + reduce ----
    // C/D layout: col = lane&15, row = (lane>>4)*4 + reg  (m89-verified)
    const int rbase = row0 + wr * 128 + ((lane >> 4) * 4);
    const int cbase = col0 + wc * 64 + fr;
    float s_all = 0.f, s_diag = 0.f;
#pragma unroll
    for (int m = 0; m < 8; ++m) {
#pragma unroll
        for (int n = 0; n < 4; ++n) {
#pragma unroll
            for (int r = 0; r < 4; ++r) {
                float Sv = acc[m][n][r];
                int row = rbase + m * 16 + r;
                int col = cbase + n * 16;
                bool dg = (row == col);
                float x = dg ? Sv : -Sv;
                float ll = fminf(x, 0.f) - __logf(1.f + __expf(-fabsf(x)));
                s_all += ll;
                if (dg) s_diag += ll;
            }
        }
    }

#pragma unroll
    for (int off = 32; off; off >>= 1) {
        s_all  += __shfl_down(s_all, off);
        s_diag += __shfl_down(s_diag, off);
    }
    __syncthreads();                    // resync before LDS reuse
    float* red = (float*)lds;
    if (lane == 0) { red[wid] = s_all; red[8 + wid] = s_diag; }
    __syncthreads();
    if (tid == 0) {
        float A = 0.f, D = 0.f;
#pragma unroll
        for (int w = 0; w < 8; ++w) { A += red[w]; D += red[8 + w]; }
        int bflat = bm * gridDim.x + bn;
        pall[bflat]  = A;
        pdiag[bflat] = D;
    }
}

// ---------------- Kernel 3: finalize ----------------
__global__ void finalize(const float* __restrict__ pall,
                         const float* __restrict__ pdiag,
                         float* __restrict__ out) {
    float a = 0.f, d = 0.f;
    for (int i = threadIdx.x; i < NBLK; i += 256) { a += pall[i]; d += pdiag[i]; }
#pragma unroll
    for (int off = 32; off; off >>= 1) {
        a += __shfl_down(a, off);
        d += __shfl_down(d, off);
    }
    __shared__ float r[8];
    int wid = threadIdx.x >> 6, lane = threadIdx.x & 63;
    if (lane == 0) { r[wid] = a; r[4 + wid] = d; }
    __syncthreads();
    if (threadIdx.x == 0) {
        float A = r[0] + r[1] + r[2] + r[3];
        float D = r[4] + r[5] + r[6] + r[7];
        out[0] = -(A + 39.f * D) / (float)BDIM;  // logLoss
        out[1] = -(40.f * D) / (float)BDIM;      // diagonalLoss
    }
}

extern "C" void kernel_launch(void* const* d_in, const int* in_sizes, int n_in,
                              void* d_out, int out_size, void* d_ws, size_t ws_size,
                              hipStream_t stream) {
    const float* enc = (const float*)d_in[0];
    const float* dec = (const float*)d_in[1];
    float* out = (float*)d_out;

    char* ws = (char*)d_ws;
    unsigned short* eb = (unsigned short*)ws;
    unsigned short* db = (unsigned short*)(ws + (size_t)16 * 1024 * 1024);
    float* pall  = (float*)(ws + (size_t)32 * 1024 * 1024);
    float* pdiag = pall + NBLK;

    reduce_cast<<<4096, 256, 0, stream>>>(
        (const float4*)enc, (const float4*)dec, (uint4*)eb, (uint4*)db);

    dim3 grid(BDIM / BN, BDIM / BM);  // (16, 16) = 256 blocks = 1/CU
    gemm_reduce<<<grid, 512, 0, stream>>>(eb, db, pall, pdiag);

    finalize<<<1, 256, 0, stream>>>(pall, pdiag, out);
}